// Round 15
// baseline (153.432 us; speedup 1.0000x reference)
//
#include <hip/hip_runtime.h>

typedef __attribute__((ext_vector_type(8))) short short8;
typedef __attribute__((ext_vector_type(4))) float f32x4;
typedef __attribute__((ext_vector_type(16))) float f32x16;

#define T_TOK 16384
#define DM 512
#define NE 8
#define BM 64
#define ROWB 1040  // padded LDS row stride: 65*16B -> bank-slot rotates by 1/row

__device__ __forceinline__ ushort f2bf(float v) {
  unsigned u = __float_as_uint(v);
  return (ushort)((u + 0x7FFFu + ((u >> 16) & 1u)) >> 16);
}

__device__ __forceinline__ unsigned pk2bf(float a, float b) {
  unsigned r;
  asm("v_cvt_pk_bf16_f32 %0, %1, %2" : "=v"(r) : "v"(a), "v"(b));
  return r;
}

#define MF(d, a, b) d = __builtin_amdgcn_mfma_f32_32x32x16_bf16(a, b, d, 0, 0, 0)

// -------- weight reorder (W1, W2, and zero-padded Wg in one launch) --------
// W1/W2: chunkid = (e*32 + kh)*16 + ft ; lane l holds
//   W[e][kh*16 + (l>>5)*8 + j][ft*32 + (l&31)]  for j=0..7 (bf16).
// WgF (A-frag for gate MFMA): frag kt (0..31); lane l holds
//   Wg[kt*16 + (l>>5)*8 + j][l&31] for col<8 else 0.
__global__ void reorder_w_kernel(const float* __restrict__ W1, const float* __restrict__ W2,
                                 const float* __restrict__ Wg,
                                 ushort* __restrict__ W1F, ushort* __restrict__ W2F,
                                 ushort* __restrict__ WgF) {
  int c = blockIdx.x * blockDim.x + threadIdx.x;  // 526336 threads (2056 blocks)
  if (c < 524288) {
    int which = c >> 18;
    c &= (1 << 18) - 1;
    const float* W = which ? W2 : W1;
    ushort* WF = which ? W2F : W1F;
    int l = c & 63;
    int chunk = c >> 6;
    int ft = chunk & 15;
    int kh = (chunk >> 4) & 31;
    int e = chunk >> 9;
    int n = ft * 32 + (l & 31);
    int k0 = kh * 16 + (l >> 5) * 8;
    const float* src = W + ((size_t)e * DM + k0) * DM + n;
    short8 v;
#pragma unroll
    for (int j = 0; j < 8; ++j) v[j] = (short)f2bf(src[(size_t)j * DM]);
    *reinterpret_cast<short8*>(WF + (size_t)c * 8) = v;
  } else {
    int c2 = c - 524288;  // 0..2047
    int l = c2 & 63;
    int kt = c2 >> 6;     // 0..31
    int col = l & 31;
    int k0 = kt * 16 + (l >> 5) * 8;
    short8 v;
#pragma unroll
    for (int j = 0; j < 8; ++j)
      v[j] = (col < NE) ? (short)f2bf(Wg[(size_t)(k0 + j) * NE + col]) : (short)0;
    *reinterpret_cast<short8*>(WgF + (size_t)c2 * 8) = v;
  }
}

// ---------------- fused MoE main kernel (gates via waves 0-1 MFMA) ----------------
// 256 blocks x 512 threads (8 waves). Wave w owns output cols [w*64, w*64+64).
// 32x32x16 MFMA, swapped operands: D[f][t] = mfma(A=W-frag, B=act-frag).
// Raw s_barrier; lgkm drain only where ds_writes must become visible.
__global__ __launch_bounds__(512, 2) void moe_main_kernel(
    const float* __restrict__ x, const ushort* __restrict__ W1F,
    const float* __restrict__ b1, const ushort* __restrict__ W2F,
    const float* __restrict__ b2, const ushort* __restrict__ WgF,
    const float* __restrict__ bg, float* __restrict__ out) {
  extern __shared__ char smem[];
  char* x_lds = smem;                        // 66560
  char* h_lds = smem + 66560;                // 66560
  float* g_lds = (float*)(smem + 133120);    // [64][9] f32 = 2304
  float* b1_lds = (float*)(smem + 135424);   // [8][512] f32 = 16384

  const int tid = threadIdx.x;
  const int lane = tid & 63;
  const int w = tid >> 6;        // wave 0..7
  const int hi = lane >> 5;      // k-half
  const int l31 = lane & 31;
  const int m0 = blockIdx.x * BM;

  const unsigned abase = (unsigned)l31 * ROWB + (unsigned)hi * 16;
  const unsigned wbase = (unsigned)l31 * ROWB + (unsigned)(w * 128 + hi * 8);

// barrier with ds_write visibility (drain lgkm first)
#define BARRIER_W()                                      \
  do {                                                   \
    asm volatile("s_waitcnt lgkmcnt(0)" ::: "memory");   \
    __builtin_amdgcn_s_barrier();                        \
  } while (0)
// plain barrier: all ds_reads before it are consumed (waited) before use;
// only read-after-barrier hazards exist on x_lds (never rewritten)
#define BARRIER_R()                                      \
  do {                                                   \
    asm volatile("" ::: "memory");                       \
    __builtin_amdgcn_s_barrier();                        \
  } while (0)

#define LDACT(lds, kt, ks, ni) \
  (*reinterpret_cast<const short8*>((lds) + abase + (ni) * (32 * ROWB) + ((kt) * 64 + (ks) * 32)))

  {  // b1 -> LDS (4096 floats = 1024 float4)
    float4* dst = (float4*)b1_lds;
    const float4* src = (const float4*)b1;
    dst[tid] = src[tid];
    dst[tid + 512] = src[tid + 512];
  }

  // stage x tile: fp32 -> bf16 via cvt_pk, padded rows
  for (int i = tid; i < BM * DM / 4; i += 512) {
    int t = i >> 7;
    int kd = (i & 127) * 4;
    float4 v = *reinterpret_cast<const float4*>(x + ((size_t)(m0 + t) << 9) + kd);
    *reinterpret_cast<uint2*>(x_lds + (unsigned)(t * ROWB + kd * 2)) =
        make_uint2(pk2bf(v.x, v.y), pk2bf(v.z, v.w));
  }
  BARRIER_W();

  const short8* wp1 = reinterpret_cast<const short8*>(W1F) + w * 128 + lane;
  const short8* wp2 = reinterpret_cast<const short8*>(W2F) + w * 128 + lane;

  f32x16 acc[2][2];
#pragma unroll
  for (int mi = 0; mi < 2; ++mi)
#pragma unroll
    for (int ni = 0; ni < 2; ++ni)
#pragma unroll
      for (int i = 0; i < 16; ++i) acc[mi][ni][i] = 0.f;

  short8 wb[3][4], ab[2][4];

  // e=0 GEMM1 prologue: kt0 -> wb[2], kt1 -> wb[0]; act kt0 -> ab[0]
#pragma unroll
  for (int ks = 0; ks < 2; ++ks)
#pragma unroll
    for (int mi = 0; mi < 2; ++mi) {
      wb[2][ks * 2 + mi] = wp1[ks * 1024 + mi * 64];
      wb[0][ks * 2 + mi] = wp1[2048 + ks * 1024 + mi * 64];
    }
#pragma unroll
  for (int ks = 0; ks < 2; ++ks)
#pragma unroll
    for (int ni = 0; ni < 2; ++ni) ab[0][ks * 2 + ni] = LDACT(x_lds, 0, ks, ni);

  if (w < 2) {
    // gates on waves 0,1 (wave w handles token half ni=w):
    // D[e][t] = sum_k Wg[k][e] * x[t][k] via 32 MFMAs per wave.
    const short8* wgf = reinterpret_cast<const short8*>(WgF) + lane;
    f32x16 ga;
#pragma unroll
    for (int i = 0; i < 16; ++i) ga[i] = 0.f;
    short8 wgb[2];
    wgb[0] = wgf[0];
#pragma unroll
    for (int s = 0; s < 32; ++s) {
      if (s < 31) wgb[(s + 1) & 1] = wgf[(s + 1) * 64];
      MF(ga, wgb[s & 1], LDACT(x_lds, s >> 1, s & 1, w));
    }
    // softmax over e for token t = w*32 + l31; lane holds e = r + 4*hi (r=0..3)
    float4 bgq = *reinterpret_cast<const float4*>(bg + hi * 4);
    float lg[4] = {ga[0] + bgq.x, ga[1] + bgq.y, ga[2] + bgq.z, ga[3] + bgq.w};
    float m = fmaxf(fmaxf(lg[0], lg[1]), fmaxf(lg[2], lg[3]));
    m = fmaxf(m, __shfl_xor(m, 32));
    float ex[4], s = 0.f;
#pragma unroll
    for (int r = 0; r < 4; ++r) { ex[r] = __expf(lg[r] - m); s += ex[r]; }
    s += __shfl_xor(s, 32);
    float inv = 1.f / s;
    int t = w * 32 + l31;
#pragma unroll
    for (int r = 0; r < 4; ++r) g_lds[t * 9 + r + 4 * hi] = ex[r] * inv;
  }
  BARRIER_W();  // g_lds ready

  for (int e = 0; e < NE; ++e) {
    const short8* we1 = wp1 + (size_t)e * 32768;
    const short8* we2 = wp2 + (size_t)e * 32768;

    // ---------- GEMM1: h^T[f][t] = sum_k W1[k][f] * x[t][k] ----------
    f32x16 hacc[2][2];
#pragma unroll
    for (int mi = 0; mi < 2; ++mi)
#pragma unroll
      for (int ni = 0; ni < 2; ++ni)
#pragma unroll
        for (int i = 0; i < 16; ++i) hacc[mi][ni][i] = 0.f;

#pragma unroll
    for (int kt = 0; kt < 16; ++kt) {
      if (kt < 14) {
#pragma unroll
        for (int ks = 0; ks < 2; ++ks)
#pragma unroll
          for (int mi = 0; mi < 2; ++mi)
            wb[(kt + 1) % 3][ks * 2 + mi] = we1[(kt + 2) * 2048 + ks * 1024 + mi * 64];
      }
      if (kt < 15) {
#pragma unroll
        for (int ks = 0; ks < 2; ++ks)
#pragma unroll
          for (int ni = 0; ni < 2; ++ni)
            ab[(kt + 1) % 2][ks * 2 + ni] = LDACT(x_lds, kt + 1, ks, ni);
      }
      __builtin_amdgcn_s_setprio(1);
#pragma unroll
      for (int ks = 0; ks < 2; ++ks)
#pragma unroll
        for (int mi = 0; mi < 2; ++mi)
#pragma unroll
          for (int ni = 0; ni < 2; ++ni)
            MF(hacc[mi][ni], wb[(kt + 2) % 3][ks * 2 + mi], ab[kt % 2][ks * 2 + ni]);
      __builtin_amdgcn_s_setprio(0);
    }

    // GEMM2 weight prologue (stays in flight across barrier): kt0 -> wb[1], kt1 -> wb[2]
#pragma unroll
    for (int ks = 0; ks < 2; ++ks)
#pragma unroll
      for (int mi = 0; mi < 2; ++mi) {
        wb[1][ks * 2 + mi] = we2[ks * 1024 + mi * 64];
        wb[2][ks * 2 + mi] = we2[2048 + ks * 1024 + mi * 64];
      }

    // epilogue: h[t][f] = relu(hacc + b1[f]) * g[t] -> h_lds (cvt_pk + b64 writes)
#pragma unroll
    for (int ni = 0; ni < 2; ++ni) {
      int t = ni * 32 + l31;
      float g = g_lds[t * 9 + e];
#pragma unroll
      for (int mi = 0; mi < 2; ++mi) {
#pragma unroll
        for (int j = 0; j < 4; ++j) {
          float4 b1q = *reinterpret_cast<const float4*>(
              b1_lds + e * DM + w * 64 + mi * 32 + j * 8 + hi * 4);
          float v0 = fmaxf(hacc[mi][ni][j * 4 + 0] + b1q.x, 0.f) * g;
          float v1 = fmaxf(hacc[mi][ni][j * 4 + 1] + b1q.y, 0.f) * g;
          float v2 = fmaxf(hacc[mi][ni][j * 4 + 2] + b1q.z, 0.f) * g;
          float v3 = fmaxf(hacc[mi][ni][j * 4 + 3] + b1q.w, 0.f) * g;
          *reinterpret_cast<uint2*>(h_lds + wbase + ni * (32 * ROWB) + mi * 64 + j * 16) =
              make_uint2(pk2bf(v0, v1), pk2bf(v2, v3));
        }
      }
    }
    BARRIER_W();  // h(e) visible

    // ---------- GEMM2: acc[d][t] += sum_f W2[f][d] * h[t][f] ----------
#pragma unroll
    for (int ks = 0; ks < 2; ++ks)
#pragma unroll
      for (int ni = 0; ni < 2; ++ni) ab[0][ks * 2 + ni] = LDACT(h_lds, 0, ks, ni);

#pragma unroll
    for (int kt = 0; kt < 16; ++kt) {
      if (kt < 14) {
#pragma unroll
        for (int ks = 0; ks < 2; ++ks)
#pragma unroll
          for (int mi = 0; mi < 2; ++mi)
            wb[kt % 3][ks * 2 + mi] = we2[(kt + 2) * 2048 + ks * 1024 + mi * 64];
      }
      if (kt < 15) {
#pragma unroll
        for (int ks = 0; ks < 2; ++ks)
#pragma unroll
          for (int ni = 0; ni < 2; ++ni)
            ab[(kt + 1) % 2][ks * 2 + ni] = LDACT(h_lds, kt + 1, ks, ni);
      }
      __builtin_amdgcn_s_setprio(1);
#pragma unroll
      for (int ks = 0; ks < 2; ++ks)
#pragma unroll
        for (int mi = 0; mi < 2; ++mi)
#pragma unroll
          for (int ni = 0; ni < 2; ++ni)
            MF(acc[mi][ni], wb[(kt + 1) % 3][ks * 2 + mi], ab[kt % 2][ks * 2 + ni]);
      __builtin_amdgcn_s_setprio(0);
    }

    // next-expert GEMM1 prologue (stays in flight across barrier)
    if (e < NE - 1) {
      const short8* wn1 = we1 + 32768;
#pragma unroll
      for (int ks = 0; ks < 2; ++ks)
#pragma unroll
        for (int mi = 0; mi < 2; ++mi) {
          wb[2][ks * 2 + mi] = wn1[ks * 1024 + mi * 64];
          wb[0][ks * 2 + mi] = wn1[2048 + ks * 1024 + mi * 64];
        }
#pragma unroll
      for (int ks = 0; ks < 2; ++ks)
#pragma unroll
        for (int ni = 0; ni < 2; ++ni) ab[0][ks * 2 + ni] = LDACT(x_lds, 0, ks, ni);
    }
    // all ds_reads of h(e) are retired before their MFMA uses above; only x_lds
    // (never rewritten) is read across this barrier -> no lgkm drain needed.
    BARRIER_R();
  }

  // fold Sum_e gate[t][e] * b2[e][d] ONCE (outside the barrier-locked loop)
#pragma unroll
  for (int e = 0; e < NE; ++e) {
    float ge0 = g_lds[l31 * 9 + e];
    float ge1 = g_lds[(32 + l31) * 9 + e];
#pragma unroll
    for (int mi = 0; mi < 2; ++mi)
#pragma unroll
      for (int j = 0; j < 4; ++j) {
        float4 b2q = *reinterpret_cast<const float4*>(
            b2 + e * DM + w * 64 + mi * 32 + j * 8 + hi * 4);
        acc[mi][0][j * 4 + 0] += ge0 * b2q.x;
        acc[mi][0][j * 4 + 1] += ge0 * b2q.y;
        acc[mi][0][j * 4 + 2] += ge0 * b2q.z;
        acc[mi][0][j * 4 + 3] += ge0 * b2q.w;
        acc[mi][1][j * 4 + 0] += ge1 * b2q.x;
        acc[mi][1][j * 4 + 1] += ge1 * b2q.y;
        acc[mi][1][j * 4 + 2] += ge1 * b2q.z;
        acc[mi][1][j * 4 + 3] += ge1 * b2q.w;
      }
  }

  // write out: per (mi,ni,j) a float4 of consecutive d
#pragma unroll
  for (int ni = 0; ni < 2; ++ni) {
    int t = m0 + ni * 32 + l31;
#pragma unroll
    for (int mi = 0; mi < 2; ++mi)
#pragma unroll
      for (int j = 0; j < 4; ++j) {
        f32x4 v;
        v[0] = acc[mi][ni][j * 4 + 0];
        v[1] = acc[mi][ni][j * 4 + 1];
        v[2] = acc[mi][ni][j * 4 + 2];
        v[3] = acc[mi][ni][j * 4 + 3];
        *reinterpret_cast<f32x4*>(out + (size_t)t * DM + w * 64 + mi * 32 + j * 8 + hi * 4) = v;
      }
  }
#undef LDACT
#undef BARRIER_W
#undef BARRIER_R
}

extern "C" void kernel_launch(void* const* d_in, const int* in_sizes, int n_in,
                              void* d_out, int out_size, void* d_ws, size_t ws_size,
                              hipStream_t stream) {
  const float* x  = (const float*)d_in[0];
  const float* W1 = (const float*)d_in[1];
  const float* b1 = (const float*)d_in[2];
  const float* W2 = (const float*)d_in[3];
  const float* b2 = (const float*)d_in[4];
  const float* Wg = (const float*)d_in[5];
  const float* bg = (const float*)d_in[6];
  float* out = (float*)d_out;

  ushort* W1F = (ushort*)d_ws;                     // 4 MiB
  ushort* W2F = (ushort*)((char*)d_ws + 4194304);  // 4 MiB
  ushort* WgF = (ushort*)((char*)d_ws + 8388608);  // 32 KiB

  hipFuncSetAttribute((const void*)moe_main_kernel,
                      hipFuncAttributeMaxDynamicSharedMemorySize, 151808);

  reorder_w_kernel<<<2056, 256, 0, stream>>>(W1, W2, Wg, W1F, W2F, WgF);
  moe_main_kernel<<<T_TOK / BM, 512, 151808, stream>>>(x, W1F, b1, W2F, b2, WgF, bg, out);
}